// Round 6
// baseline (293.393 us; speedup 1.0000x reference)
//
#include <hip/hip_runtime.h>
#include <hip/hip_cooperative_groups.h>

namespace cg = cooperative_groups;

#define HH 128
#define WW 128
#define CC 64
#define OO 64
#define NC 35
#define NPIX (HH*WW)        // per-batch pixels = 16384
#define LISTST NPIX
#define NBKT (2*NC)         // 70 buckets (b,label)
#define XSTR 68             // mv LDS row stride: 64 pixels + 4 pad (conflict-free reads)
#define GRID 512            // cooperative grid: 2 blocks/CU guaranteed co-resident

// Workspace layout:
//   [0,     8192)   gpad[128][16]  one 64B line per (b,o): [0]=sum, [1]=sumsq
//   [8192,  8472)   cnt[70]
//   [16384, 147456) lab[2*16384] int
//   [256 KiB, +4.6 MiB) list[70*16384] int
//   [ 8 MiB)        xT : (b,pix,c) = x + conv-scalar, pixel-major
//   [16 MiB)        yT : (b,pix,o) pre-norm output, pixel-major

#define FMA_PX(A, XV) \
    A.x = fmaf((XV), qv.x, A.x); \
    A.y = fmaf((XV), qv.y, A.y); \
    A.z = fmaf((XV), qv.z, A.z); \
    A.w = fmaf((XV), qv.w, A.w);

// ============================ fused cooperative kernel ============================
// Phase 1: conv scalar + argmax -> lab + transpose x(+s) -> xT   (1024 tiles, 2/block)
// Phase 2: bucket pixels by (b,label) via prefix-scan (blocks 0..69); zero gpad (block 70)
// Phase 3: label-grouped matvec (block tasks), stats -> gpad fire-and-forget atomics
// Phase 4: instance-norm finalize + transpose yT -> out + leaky relu (512 tiles)
__global__ void __launch_bounds__(256, 2) fused_kernel(
    const float* __restrict__ x, const float* __restrict__ layout,
    const float* __restrict__ pr, const float* __restrict__ cw,
    const float* __restrict__ cb, const float* __restrict__ Wt,
    const float* __restrict__ bt, const float* __restrict__ pl,
    float* __restrict__ out, float* __restrict__ gpad, int* __restrict__ cnt,
    int* __restrict__ lab, int* __restrict__ list,
    float* __restrict__ xT, float* __restrict__ yT)
{
    __shared__ __align__(16) union {
        struct { float xh[64*33]; float s[32]; } prep;                       // 8.6 KB
        struct { int wsum[4]; } bin;
        struct { float xh[64*XSTR]; float red[4][64][2]; int pib[64]; int ntask; } mv; // 19.7 KB
        struct { float tmat[64*65]; float mean[64]; float rstd[64]; } norm;  // 17.2 KB
    } u;

    cg::grid_group gg = cg::this_grid();

    const int t    = threadIdx.x;
    const int bid  = blockIdx.x;
    const int wv   = t >> 6;
    const int lane = t & 63;
    const int i15  = lane & 15;
    const int ihi  = lane >> 4;

    // ---------------- Phase 1: prep (2 tiles of 32 pixels per block) ----------------
    for (int tile = bid; tile < 1024; tile += GRID) {
        const int b  = tile >> 9;
        const int rem = tile & 511;
        const int h  = rem >> 2;
        const int w0 = (rem & 3) << 5;

        if (wv == 0 && lane < 32) {
            int w = w0 + lane;
            float pxv = (float)h * (2.0f/128.0f) - 1.0f;
            float pyv = (float)w * (2.0f/128.0f) - 1.0f;
            float pl0 = pl[h*WW + w];
            float pl1 = pl[NPIX + h*WW + w];
            float pr0 = pr[((b*2+0)*HH + h)*WW + w];
            float pr1 = pr[((b*2+1)*HH + h)*WW + w];
            int kx = w % 3, kyy = h % 3;
            const float C1 = -0.5f, S1 = 0.86602540378443864676f;
            float xcv = (kx==0)  ? 1.0f : C1;
            float xsv = (kx==0)  ? 0.0f : ((kx==1)  ? S1 : -S1);
            float ycv = (kyy==0) ? 1.0f : C1;
            float ysv = (kyy==0) ? 0.0f : ((kyy==1) ? S1 : -S1);
            u.prep.s[lane] = cb[0] + pxv*cw[0] + pyv*cw[1] + pl0*cw[2] + pl1*cw[3]
                      + pr0*cw[4] + pr1*cw[5] + xcv*cw[6] + xsv*cw[7]
                      + ycv*cw[8] + ysv*cw[9];
        }

        if (wv == 1 && lane < 32) {      // argmax, first-max wins like jnp.argmax
            int w = w0 + lane;
            const float* lp = layout + ((size_t)(b*NC)*HH + h)*WW + w;
            float best = lp[0]; int bi = 0;
            #pragma unroll
            for (int c = 1; c < NC; ++c) {
                float v = lp[(size_t)c*NPIX];
                if (v > best) { best = v; bi = c; }
            }
            lab[b*NPIX + h*WW + w] = bi;
        }

        {   // stage raw x into LDS (coalesced)
            int p = t & 31, c0 = t >> 5;
            const float* xp = x + ((size_t)(b*CC)*HH + h)*WW + w0 + p;
            #pragma unroll
            for (int k = 0; k < 8; ++k) {
                int c = c0 + 8*k;
                u.prep.xh[c*33 + p] = xp[(size_t)c*NPIX];
            }
        }
        __syncthreads();

        {   // transpose-write xT[pix][c] = x + s
            int p = t >> 3, c0 = (t & 7) << 3;
            float sp = u.prep.s[p];
            float4 a, d;
            a.x = u.prep.xh[(c0+0)*33+p] + sp;
            a.y = u.prep.xh[(c0+1)*33+p] + sp;
            a.z = u.prep.xh[(c0+2)*33+p] + sp;
            a.w = u.prep.xh[(c0+3)*33+p] + sp;
            d.x = u.prep.xh[(c0+4)*33+p] + sp;
            d.y = u.prep.xh[(c0+5)*33+p] + sp;
            d.z = u.prep.xh[(c0+6)*33+p] + sp;
            d.w = u.prep.xh[(c0+7)*33+p] + sp;
            float* dst = xT + (((size_t)b*NPIX + h*WW + w0 + p) << 6) + c0;
            *(float4*)dst       = a;
            *(float4*)(dst + 4) = d;
        }
        __syncthreads();     // s_xh/s_s reused next tile iteration
    }

    gg.sync();   // lab, xT visible grid-wide

    // ---------------- Phase 2: bin (blocks 0..69) + zero gpad (block 70) ----------------
    if (bid < NBKT) {
        const int bkt = bid;
        const int b   = (bkt >= NC) ? 1 : 0;
        const int l   = bkt - b*NC;
        const int* lp = lab + b*NPIX;

        int m = 0;
        #pragma unroll 8
        for (int j = 0; j < 64; ++j) m += (lp[j*256 + t] == l) ? 1 : 0;

        int v = m;
        #pragma unroll
        for (int d = 1; d < 64; d <<= 1) {
            int o = __shfl_up(v, d);
            if (lane >= d) v += o;
        }
        if (lane == 63) u.bin.wsum[wv] = v;
        __syncthreads();
        int wbase = 0;
        #pragma unroll
        for (int k = 0; k < 4; ++k) wbase += (k < wv) ? u.bin.wsum[k] : 0;
        int base = wbase + v - m;
        if (t == 0) cnt[bkt] = u.bin.wsum[0] + u.bin.wsum[1] + u.bin.wsum[2] + u.bin.wsum[3];

        int* dst = list + bkt*LISTST;
        int o = base;
        #pragma unroll 8
        for (int j = 0; j < 64; ++j) {
            int p = j*256 + t;
            if (lp[p] == l) dst[o++] = p;
        }
    } else if (bid == NBKT) {
        for (int i = t; i < 2048; i += 256) gpad[i] = 0.0f;
    }

    gg.sync();   // cnt, list, gpad visible grid-wide

    // ---------------- Phase 3: label-grouped matvec ----------------
    if (t < 64) {   // tight task bound from max bucket count
        int c1 = cnt[(lane < NBKT) ? lane : (NBKT-1)];
        int c2 = cnt[(lane < (NBKT-64)) ? 64 + lane : (NBKT-1)];
        int m  = c1 > c2 ? c1 : c2;
        #pragma unroll
        for (int d = 32; d >= 1; d >>= 1) {
            int o = __shfl_xor(m, d);
            m = m > o ? m : o;
        }
        if (lane == 0) u.mv.ntask = NBKT * ((m + 63) >> 6);
    }
    __syncthreads();
    const int ntask = u.mv.ntask;

    for (int task = bid; task < ntask; task += GRID) {
        const int bkt   = task % NBKT;
        const int chunk = task / NBKT;
        const int n     = cnt[bkt];
        const int base  = chunk << 6;
        if (base >= n) continue;             // block-uniform
        const int b = (bkt >= NC) ? 1 : 0;
        const int l = bkt - b*NC;

        __syncthreads();   // protect mv LDS from previous task's readers

        {   // stage 64 pixels transposed into u.mv.xh[c][p] + pixel ids
            const int p   = t & 63;
            const int q   = t >> 6;
            const int pi  = base + p;
            const int pib = list[bkt*LISTST + ((pi < n) ? pi : (n-1))];
            if (q == 0) u.mv.pib[p] = pib;
            const float* xp = xT + (((size_t)b*NPIX + pib) << 6) + (q << 4);
            #pragma unroll
            for (int j = 0; j < 4; ++j) {
                float4 v = ((const float4*)xp)[j];
                const int c = (q << 4) + (j << 2);
                u.mv.xh[(c+0)*XSTR + p] = v.x;
                u.mv.xh[(c+1)*XSTR + p] = v.y;
                u.mv.xh[(c+2)*XSTR + p] = v.z;
                u.mv.xh[(c+3)*XSTR + p] = v.w;
            }
        }
        __syncthreads();

        // compute: wave wv owns pixels wv*16..wv*16+15, two groups of 8
        const float4* __restrict__ W4 = ((const float4*)(Wt + (size_t)l*4096)) + lane;
        const float4 bb = *((const float4*)(bt + (size_t)l*64) + i15);
        float4 sumv = make_float4(0,0,0,0), ssv = make_float4(0,0,0,0);

        #pragma unroll
        for (int g = 0; g < 2; ++g) {
            const int p0 = (wv << 4) + (g << 3);
            float4 a[8];
            #pragma unroll
            for (int pj = 0; pj < 8; ++pj) a[pj] = make_float4(0,0,0,0);

            #pragma unroll
            for (int tt = 0; tt < 16; ++tt) {
                const float4 qv = W4[tt << 6];                 // c = 4tt+ihi, o-quad 4*i15
                const int    c  = (tt << 2) + ihi;
                const float4 xa = *(const float4*)&u.mv.xh[c*XSTR + p0];
                const float4 xb = *(const float4*)&u.mv.xh[c*XSTR + p0 + 4];
                FMA_PX(a[0], xa.x) FMA_PX(a[1], xa.y) FMA_PX(a[2], xa.z) FMA_PX(a[3], xa.w)
                FMA_PX(a[4], xb.x) FMA_PX(a[5], xb.y) FMA_PX(a[6], xb.z) FMA_PX(a[7], xb.w)
            }

            #pragma unroll
            for (int pj = 0; pj < 8; ++pj) {
                a[pj].x += __shfl_xor(a[pj].x, 16); a[pj].y += __shfl_xor(a[pj].y, 16);
                a[pj].z += __shfl_xor(a[pj].z, 16); a[pj].w += __shfl_xor(a[pj].w, 16);
                a[pj].x += __shfl_xor(a[pj].x, 32); a[pj].y += __shfl_xor(a[pj].y, 32);
                a[pj].z += __shfl_xor(a[pj].z, 32); a[pj].w += __shfl_xor(a[pj].w, 32);
            }

            if (ihi == 0) {
                #pragma unroll
                for (int pj = 0; pj < 8; ++pj) {
                    const bool  vld = (base + p0 + pj) < n;
                    const float msk = vld ? 1.0f : 0.0f;
                    float y0 = (a[pj].x + bb.x) * msk;
                    float y1 = (a[pj].y + bb.y) * msk;
                    float y2 = (a[pj].z + bb.z) * msk;
                    float y3 = (a[pj].w + bb.w) * msk;
                    if (vld) {
                        float* yp = yT + (((size_t)b*NPIX + u.mv.pib[p0+pj]) << 6) + (i15 << 2);
                        *(float4*)yp = make_float4(y0, y1, y2, y3);
                    }
                    sumv.x += y0; ssv.x += y0*y0;
                    sumv.y += y1; ssv.y += y1*y1;
                    sumv.z += y2; ssv.z += y2*y2;
                    sumv.w += y3; ssv.w += y3*y3;
                }
            }
        }

        if (ihi == 0) {
            const int o = i15 << 2;
            u.mv.red[wv][o+0][0] = sumv.x; u.mv.red[wv][o+0][1] = ssv.x;
            u.mv.red[wv][o+1][0] = sumv.y; u.mv.red[wv][o+1][1] = ssv.y;
            u.mv.red[wv][o+2][0] = sumv.z; u.mv.red[wv][o+2][1] = ssv.z;
            u.mv.red[wv][o+3][0] = sumv.w; u.mv.red[wv][o+3][1] = ssv.w;
        }
        __syncthreads();
        if (t < 64) {
            float S  = u.mv.red[0][t][0] + u.mv.red[1][t][0] + u.mv.red[2][t][0] + u.mv.red[3][t][0];
            float SS = u.mv.red[0][t][1] + u.mv.red[1][t][1] + u.mv.red[2][t][1] + u.mv.red[3][t][1];
            float* gp = gpad + (((b << 6) + t) << 4);   // private 64B line per (b,o)
            atomicAdd(gp + 0, S);                        // fire-and-forget
            atomicAdd(gp + 1, SS);
        }
    }

    gg.sync();   // yT, gpad visible grid-wide

    // ---------------- Phase 4: instance-norm + leaky relu (512 tiles, 1/block) ----------------
    {
        const int tile = bid;          // 512: b(2) x h(128) x wt(2)
        const int b    = tile >> 8;
        const int rem  = tile & 255;
        const int h    = rem >> 1;
        const int w0   = (rem & 1) << 6;

        if (t < 64) {
            const float invN = 1.0f/16384.0f;
            const float* gp = gpad + (((b << 6) + t) << 4);
            float mean = gp[0] * invN;
            float var  = gp[1] * invN - mean*mean;
            u.norm.mean[t] = mean;
            u.norm.rstd[t] = rsqrtf(var + 1e-5f);
        }
        {
            const int p = t >> 2, q = t & 3;
            const float4* yp = (const float4*)(yT + (((size_t)b*NPIX + h*WW + w0 + p) << 6) + (q << 4));
            #pragma unroll
            for (int j = 0; j < 4; ++j) {
                float4 v = yp[j];
                int o = (q << 4) + (j << 2);
                u.norm.tmat[(o+0)*65 + p] = v.x;
                u.norm.tmat[(o+1)*65 + p] = v.y;
                u.norm.tmat[(o+2)*65 + p] = v.z;
                u.norm.tmat[(o+3)*65 + p] = v.w;
            }
        }
        __syncthreads();
        {
            const int o = t >> 2, q = t & 3;
            const float mean = u.norm.mean[o];
            const float r    = u.norm.rstd[o];
            float* op = out + (((size_t)(b*OO + o)*HH + h)*WW) + w0 + (q << 4);
            #pragma unroll
            for (int j = 0; j < 4; ++j) {
                int wq = (q << 4) + (j << 2);
                float4 v;
                v.x = u.norm.tmat[o*65 + wq + 0];
                v.y = u.norm.tmat[o*65 + wq + 1];
                v.z = u.norm.tmat[o*65 + wq + 2];
                v.w = u.norm.tmat[o*65 + wq + 3];
                float a_;
                a_ = (v.x - mean) * r; v.x = (a_ >= 0.f) ? a_ : 0.01f*a_;
                a_ = (v.y - mean) * r; v.y = (a_ >= 0.f) ? a_ : 0.01f*a_;
                a_ = (v.z - mean) * r; v.z = (a_ >= 0.f) ? a_ : 0.01f*a_;
                a_ = (v.w - mean) * r; v.w = (a_ >= 0.f) ? a_ : 0.01f*a_;
                ((float4*)op)[j] = v;
            }
        }
    }
}

// ============================ fallback kernels (round-5 pipeline) ============================

__global__ __launch_bounds__(256) void prep_kernel(
    const float* __restrict__ x, const float* __restrict__ layout,
    const float* __restrict__ pr, const float* __restrict__ cw,
    const float* __restrict__ cb, const float* __restrict__ pl,
    float* __restrict__ xT, int* __restrict__ lab)
{
    __shared__ float s_xh[64*33];
    __shared__ float s_s[32];
    const int t = threadIdx.x, wv = t >> 6, lane = t & 63;
    const int tile = blockIdx.x, b = tile >> 9, rem = tile & 511;
    const int h = rem >> 2, w0 = (rem & 3) << 5;

    if (wv == 0 && lane < 32) {
        int w = w0 + lane;
        float pxv = (float)h * (2.0f/128.0f) - 1.0f;
        float pyv = (float)w * (2.0f/128.0f) - 1.0f;
        float pl0 = pl[h*WW + w];
        float pl1 = pl[NPIX + h*WW + w];
        float pr0 = pr[((b*2+0)*HH + h)*WW + w];
        float pr1 = pr[((b*2+1)*HH + h)*WW + w];
        int kx = w % 3, kyy = h % 3;
        const float C1 = -0.5f, S1 = 0.86602540378443864676f;
        float xcv = (kx==0)  ? 1.0f : C1;
        float xsv = (kx==0)  ? 0.0f : ((kx==1)  ? S1 : -S1);
        float ycv = (kyy==0) ? 1.0f : C1;
        float ysv = (kyy==0) ? 0.0f : ((kyy==1) ? S1 : -S1);
        s_s[lane] = cb[0] + pxv*cw[0] + pyv*cw[1] + pl0*cw[2] + pl1*cw[3]
                  + pr0*cw[4] + pr1*cw[5] + xcv*cw[6] + xsv*cw[7]
                  + ycv*cw[8] + ysv*cw[9];
    }
    if (wv == 1 && lane < 32) {
        int w = w0 + lane;
        const float* lp = layout + ((size_t)(b*NC)*HH + h)*WW + w;
        float best = lp[0]; int bi = 0;
        #pragma unroll
        for (int c = 1; c < NC; ++c) {
            float v = lp[(size_t)c*NPIX];
            if (v > best) { best = v; bi = c; }
        }
        lab[b*NPIX + h*WW + w] = bi;
    }
    {
        int p = t & 31, c0 = t >> 5;
        const float* xp = x + ((size_t)(b*CC)*HH + h)*WW + w0 + p;
        #pragma unroll
        for (int k = 0; k < 8; ++k) { int c = c0 + 8*k; s_xh[c*33 + p] = xp[(size_t)c*NPIX]; }
    }
    __syncthreads();
    {
        int p = t >> 3, c0 = (t & 7) << 3;
        float sp = s_s[p];
        float4 a, d;
        a.x = s_xh[(c0+0)*33+p] + sp; a.y = s_xh[(c0+1)*33+p] + sp;
        a.z = s_xh[(c0+2)*33+p] + sp; a.w = s_xh[(c0+3)*33+p] + sp;
        d.x = s_xh[(c0+4)*33+p] + sp; d.y = s_xh[(c0+5)*33+p] + sp;
        d.z = s_xh[(c0+6)*33+p] + sp; d.w = s_xh[(c0+7)*33+p] + sp;
        float* dst = xT + (((size_t)b*NPIX + h*WW + w0 + p) << 6) + c0;
        *(float4*)dst = a; *(float4*)(dst + 4) = d;
    }
}

__global__ __launch_bounds__(256) void bin_kernel(
    const int* __restrict__ lab, int* __restrict__ cnt, int* __restrict__ list)
{
    __shared__ int s_wsum[4];
    const int t = threadIdx.x, lane = t & 63, wv = t >> 6;
    const int bkt = blockIdx.x, b = (bkt >= NC) ? 1 : 0, l = bkt - b*NC;
    const int* lp = lab + b*NPIX;
    int m = 0;
    #pragma unroll 8
    for (int j = 0; j < 64; ++j) m += (lp[j*256 + t] == l) ? 1 : 0;
    int v = m;
    #pragma unroll
    for (int d = 1; d < 64; d <<= 1) { int o = __shfl_up(v, d); if (lane >= d) v += o; }
    if (lane == 63) s_wsum[wv] = v;
    __syncthreads();
    int wbase = 0;
    #pragma unroll
    for (int k = 0; k < 4; ++k) wbase += (k < wv) ? s_wsum[k] : 0;
    int base = wbase + v - m;
    if (t == 0) cnt[bkt] = s_wsum[0] + s_wsum[1] + s_wsum[2] + s_wsum[3];
    int* dst = list + bkt*LISTST;
    int o = base;
    #pragma unroll 8
    for (int j = 0; j < 64; ++j) { int p = j*256 + t; if (lp[p] == l) dst[o++] = p; }
}

__global__ __launch_bounds__(256) void mv_kernel(
    const float* __restrict__ Wt, const float* __restrict__ bt,
    const float* __restrict__ xT, const int* __restrict__ cnt,
    const int* __restrict__ list, float* __restrict__ yT,
    float* __restrict__ gpad)
{
    __shared__ __align__(16) float s_xh[64*XSTR];
    __shared__ int   s_pib[64];
    __shared__ float s_red[4][64][2];
    __shared__ int   s_ntask;
    const int t = threadIdx.x, wv = t >> 6, lane = t & 63;
    const int i15 = lane & 15, ihi = lane >> 4;

    if (t < 64) {
        int c1 = cnt[(lane < NBKT) ? lane : (NBKT-1)];
        int c2 = cnt[(lane < (NBKT-64)) ? 64 + lane : (NBKT-1)];
        int m  = c1 > c2 ? c1 : c2;
        #pragma unroll
        for (int d = 32; d >= 1; d >>= 1) { int o = __shfl_xor(m, d); m = m > o ? m : o; }
        if (lane == 0) s_ntask = NBKT * ((m + 63) >> 6);
    }
    __syncthreads();
    const int ntask = s_ntask;

    for (int task = blockIdx.x; task < ntask; task += gridDim.x) {
        const int bkt = task % NBKT, chunk = task / NBKT;
        const int n = cnt[bkt], base = chunk << 6;
        if (base >= n) continue;
        const int b = (bkt >= NC) ? 1 : 0, l = bkt - b*NC;
        __syncthreads();
        {
            const int p = t & 63, q = t >> 6, pi = base + p;
            const int pib = list[bkt*LISTST + ((pi < n) ? pi : (n-1))];
            if (q == 0) s_pib[p] = pib;
            const float* xp = xT + (((size_t)b*NPIX + pib) << 6) + (q << 4);
            #pragma unroll
            for (int j = 0; j < 4; ++j) {
                float4 v = ((const float4*)xp)[j];
                const int c = (q << 4) + (j << 2);
                s_xh[(c+0)*XSTR + p] = v.x; s_xh[(c+1)*XSTR + p] = v.y;
                s_xh[(c+2)*XSTR + p] = v.z; s_xh[(c+3)*XSTR + p] = v.w;
            }
        }
        __syncthreads();
        const float4* __restrict__ W4 = ((const float4*)(Wt + (size_t)l*4096)) + lane;
        const float4 bb = *((const float4*)(bt + (size_t)l*64) + i15);
        float4 sumv = make_float4(0,0,0,0), ssv = make_float4(0,0,0,0);
        #pragma unroll
        for (int g = 0; g < 2; ++g) {
            const int p0 = (wv << 4) + (g << 3);
            float4 a[8];
            #pragma unroll
            for (int pj = 0; pj < 8; ++pj) a[pj] = make_float4(0,0,0,0);
            #pragma unroll
            for (int tt = 0; tt < 16; ++tt) {
                const float4 qv = W4[tt << 6];
                const int    c  = (tt << 2) + ihi;
                const float4 xa = *(const float4*)&s_xh[c*XSTR + p0];
                const float4 xb = *(const float4*)&s_xh[c*XSTR + p0 + 4];
                FMA_PX(a[0], xa.x) FMA_PX(a[1], xa.y) FMA_PX(a[2], xa.z) FMA_PX(a[3], xa.w)
                FMA_PX(a[4], xb.x) FMA_PX(a[5], xb.y) FMA_PX(a[6], xb.z) FMA_PX(a[7], xb.w)
            }
            #pragma unroll
            for (int pj = 0; pj < 8; ++pj) {
                a[pj].x += __shfl_xor(a[pj].x, 16); a[pj].y += __shfl_xor(a[pj].y, 16);
                a[pj].z += __shfl_xor(a[pj].z, 16); a[pj].w += __shfl_xor(a[pj].w, 16);
                a[pj].x += __shfl_xor(a[pj].x, 32); a[pj].y += __shfl_xor(a[pj].y, 32);
                a[pj].z += __shfl_xor(a[pj].z, 32); a[pj].w += __shfl_xor(a[pj].w, 32);
            }
            if (ihi == 0) {
                #pragma unroll
                for (int pj = 0; pj < 8; ++pj) {
                    const bool  vld = (base + p0 + pj) < n;
                    const float msk = vld ? 1.0f : 0.0f;
                    float y0 = (a[pj].x + bb.x) * msk;
                    float y1 = (a[pj].y + bb.y) * msk;
                    float y2 = (a[pj].z + bb.z) * msk;
                    float y3 = (a[pj].w + bb.w) * msk;
                    if (vld) {
                        float* yp = yT + (((size_t)b*NPIX + s_pib[p0+pj]) << 6) + (i15 << 2);
                        *(float4*)yp = make_float4(y0, y1, y2, y3);
                    }
                    sumv.x += y0; ssv.x += y0*y0;
                    sumv.y += y1; ssv.y += y1*y1;
                    sumv.z += y2; ssv.z += y2*y2;
                    sumv.w += y3; ssv.w += y3*y3;
                }
            }
        }
        if (ihi == 0) {
            const int o = i15 << 2;
            s_red[wv][o+0][0] = sumv.x; s_red[wv][o+0][1] = ssv.x;
            s_red[wv][o+1][0] = sumv.y; s_red[wv][o+1][1] = ssv.y;
            s_red[wv][o+2][0] = sumv.z; s_red[wv][o+2][1] = ssv.z;
            s_red[wv][o+3][0] = sumv.w; s_red[wv][o+3][1] = ssv.w;
        }
        __syncthreads();
        if (t < 64) {
            float S  = s_red[0][t][0] + s_red[1][t][0] + s_red[2][t][0] + s_red[3][t][0];
            float SS = s_red[0][t][1] + s_red[1][t][1] + s_red[2][t][1] + s_red[3][t][1];
            float* gp = gpad + (((b << 6) + t) << 4);
            atomicAdd(gp + 0, S);
            atomicAdd(gp + 1, SS);
        }
    }
}

__global__ __launch_bounds__(256) void norm_kernel(
    const float* __restrict__ yT, const float* __restrict__ gpad,
    float* __restrict__ out)
{
    __shared__ float s_t[64*65];
    __shared__ float s_mean[64];
    __shared__ float s_rstd[64];
    const int t = threadIdx.x, tile = blockIdx.x;
    const int b = tile >> 8, rem = tile & 255, h = rem >> 1, w0 = (rem & 1) << 6;
    if (t < 64) {
        const float invN = 1.0f/16384.0f;
        const float* gp = gpad + (((b << 6) + t) << 4);
        float mean = gp[0] * invN;
        float var  = gp[1] * invN - mean*mean;
        s_mean[t] = mean;
        s_rstd[t] = rsqrtf(var + 1e-5f);
    }
    {
        const int p = t >> 2, q = t & 3;
        const float4* yp = (const float4*)(yT + (((size_t)b*NPIX + h*WW + w0 + p) << 6) + (q << 4));
        #pragma unroll
        for (int j = 0; j < 4; ++j) {
            float4 v = yp[j];
            int o = (q << 4) + (j << 2);
            s_t[(o+0)*65 + p] = v.x; s_t[(o+1)*65 + p] = v.y;
            s_t[(o+2)*65 + p] = v.z; s_t[(o+3)*65 + p] = v.w;
        }
    }
    __syncthreads();
    {
        const int o = t >> 2, q = t & 3;
        const float mean = s_mean[o], r = s_rstd[o];
        float* op = out + (((size_t)(b*OO + o)*HH + h)*WW) + w0 + (q << 4);
        #pragma unroll
        for (int j = 0; j < 4; ++j) {
            int wq = (q << 4) + (j << 2);
            float4 v;
            v.x = s_t[o*65 + wq + 0]; v.y = s_t[o*65 + wq + 1];
            v.z = s_t[o*65 + wq + 2]; v.w = s_t[o*65 + wq + 3];
            float a_;
            a_ = (v.x - mean) * r; v.x = (a_ >= 0.f) ? a_ : 0.01f*a_;
            a_ = (v.y - mean) * r; v.y = (a_ >= 0.f) ? a_ : 0.01f*a_;
            a_ = (v.z - mean) * r; v.z = (a_ >= 0.f) ? a_ : 0.01f*a_;
            a_ = (v.w - mean) * r; v.w = (a_ >= 0.f) ? a_ : 0.01f*a_;
            ((float4*)op)[j] = v;
        }
    }
}

extern "C" void kernel_launch(void* const* d_in, const int* in_sizes, int n_in,
                              void* d_out, int out_size, void* d_ws, size_t ws_size,
                              hipStream_t stream) {
    const float* x      = (const float*)d_in[0];
    const float* layout = (const float*)d_in[1];
    const float* pr     = (const float*)d_in[2];
    const float* cw     = (const float*)d_in[3];
    const float* cb     = (const float*)d_in[4];
    const float* Wt     = (const float*)d_in[5];
    const float* bt     = (const float*)d_in[6];
    const float* pl     = (const float*)d_in[7];
    float* out = (float*)d_out;

    char*  ws   = (char*)d_ws;
    float* gpad = (float*)ws;                       // [128][16] f32, 8 KB
    int*   cnt  = (int*)(ws + 8192);                // [70]
    int*   lab  = (int*)(ws + 16384);               // [2][16384]
    int*   list = (int*)(ws + (256u << 10));        // [70][16384]
    float* xT   = (float*)(ws + (8u  << 20));
    float* yT   = (float*)(ws + (16u << 20));

    void* kargs[] = {
        (void*)&x, (void*)&layout, (void*)&pr, (void*)&cw, (void*)&cb,
        (void*)&Wt, (void*)&bt, (void*)&pl, (void*)&out,
        (void*)&gpad, (void*)&cnt, (void*)&lab, (void*)&list,
        (void*)&xT, (void*)&yT
    };
    hipError_t e = hipLaunchCooperativeKernel((const void*)fused_kernel,
                                              dim3(GRID), dim3(256), kargs, 0, stream);
    if (e != hipSuccess) {
        // fallback: round-5 4-kernel pipeline
        hipMemsetAsync(gpad, 0, 8192, stream);
        prep_kernel<<<1024, 256, 0, stream>>>(x, layout, pr, cw, cb, pl, xT, lab);
        bin_kernel <<<  70, 256, 0, stream>>>(lab, cnt, list);
        mv_kernel  <<<1024, 256, 0, stream>>>(Wt, bt, xT, cnt, list, yT, gpad);
        norm_kernel<<< 512, 256, 0, stream>>>(yT, gpad, out);
    }
}

// Round 7
// 128.230 us; speedup vs baseline: 2.2880x; 2.2880x over previous
//
#include <hip/hip_runtime.h>

#define HH 128
#define WW 128
#define CC 64
#define OO 64
#define NC 35
#define NPIX (HH*WW)        // per-batch pixels = 16384
#define LISTST NPIX
#define NBKT (2*NC)         // 70 buckets (b,label)
#define MSTR 36             // mv LDS row stride: 32 pixels + 4 pad (conflict-free, round-0 proven)

// Workspace layout:
//   [0,     8192)   gpad[128][16]  one 64B line per (b,o): [0]=sum, [1]=sumsq (zeroed by prep blocks 0..7)
//   [8192,  8472)   cnt[70]
//   [16384, 147456) lab[2*16384] int
//   [256 KiB, +4.6 MiB) list[70*16384] int
//   [ 8 MiB)        xT : (b,pix,c) = x + conv-scalar, pixel-major
//   [16 MiB)        yT : (b,pix,o) pre-norm output, pixel-major

// Kernel 1: conv scalar + argmax -> lab + transpose x(+s) -> xT. Blocks 0..7 also zero gpad.
__global__ __launch_bounds__(256) void prep_kernel(
    const float* __restrict__ x, const float* __restrict__ layout,
    const float* __restrict__ pr, const float* __restrict__ cw,
    const float* __restrict__ cb, const float* __restrict__ pl,
    float* __restrict__ xT, int* __restrict__ lab, float* __restrict__ gpad)
{
    __shared__ float s_xh[64*33];   // [c][p] stride 33, 32 pixels -> conflict-free
    __shared__ float s_s[32];

    const int t    = threadIdx.x;
    const int wv   = t >> 6;
    const int lane = t & 63;
    const int tile = blockIdx.x;     // 1024: b(2) x h(128) x wq(4)
    const int b    = tile >> 9;
    const int rem  = tile & 511;
    const int h    = rem >> 2;
    const int w0   = (rem & 3) << 5;

    if (tile < 8) gpad[(tile << 8) + t] = 0.0f;   // zero stats lines (read only by mv, later dispatch)

    // conv scalar s for 32 pixels (wave 0, lanes 0..31)
    if (wv == 0 && lane < 32) {
        int w = w0 + lane;
        float pxv = (float)h * (2.0f/128.0f) - 1.0f;
        float pyv = (float)w * (2.0f/128.0f) - 1.0f;
        float pl0 = pl[h*WW + w];
        float pl1 = pl[NPIX + h*WW + w];
        float pr0 = pr[((b*2+0)*HH + h)*WW + w];
        float pr1 = pr[((b*2+1)*HH + h)*WW + w];
        int kx = w % 3, kyy = h % 3;
        const float C1 = -0.5f, S1 = 0.86602540378443864676f;
        float xcv = (kx==0)  ? 1.0f : C1;
        float xsv = (kx==0)  ? 0.0f : ((kx==1)  ? S1 : -S1);
        float ycv = (kyy==0) ? 1.0f : C1;
        float ysv = (kyy==0) ? 0.0f : ((kyy==1) ? S1 : -S1);
        s_s[lane] = cb[0] + pxv*cw[0] + pyv*cw[1] + pl0*cw[2] + pl1*cw[3]
                  + pr0*cw[4] + pr1*cw[5] + xcv*cw[6] + xsv*cw[7]
                  + ycv*cw[8] + ysv*cw[9];
    }

    // argmax over layout channels (wave 1, lanes 0..31); first-max wins like jnp.argmax
    if (wv == 1 && lane < 32) {
        int w = w0 + lane;
        const float* lp = layout + ((size_t)(b*NC)*HH + h)*WW + w;
        float best = lp[0]; int bi = 0;
        #pragma unroll
        for (int c = 1; c < NC; ++c) {
            float v = lp[(size_t)c*NPIX];
            if (v > best) { best = v; bi = c; }
        }
        lab[b*NPIX + h*WW + w] = bi;      // plain coalesced store
    }

    // stage raw x into LDS (coalesced)
    {
        int p = t & 31, c0 = t >> 5;
        const float* xp = x + ((size_t)(b*CC)*HH + h)*WW + w0 + p;
        #pragma unroll
        for (int k = 0; k < 8; ++k) {
            int c = c0 + 8*k;
            s_xh[c*33 + p] = xp[(size_t)c*NPIX];
        }
    }
    __syncthreads();

    // transpose-write xT[pix][c] = x + s  (coalesced 8 KB/block contiguous)
    {
        int p = t >> 3, c0 = (t & 7) << 3;
        float sp = s_s[p];
        float4 a, d;
        a.x = s_xh[(c0+0)*33+p] + sp;
        a.y = s_xh[(c0+1)*33+p] + sp;
        a.z = s_xh[(c0+2)*33+p] + sp;
        a.w = s_xh[(c0+3)*33+p] + sp;
        d.x = s_xh[(c0+4)*33+p] + sp;
        d.y = s_xh[(c0+5)*33+p] + sp;
        d.z = s_xh[(c0+6)*33+p] + sp;
        d.w = s_xh[(c0+7)*33+p] + sp;
        float* dst = xT + (((size_t)b*NPIX + h*WW + w0 + p) << 6) + c0;
        *(float4*)dst       = a;
        *(float4*)(dst + 4) = d;
    }
}

// Kernel 1b: bucket the pixels. One 1024-thread block per (b,label) bucket: 16 coalesced
// scan iterations per pass (was 64 with 256 thr). Shfl prefix-scan; plain stores only.
__global__ __launch_bounds__(1024) void bin_kernel(
    const int* __restrict__ lab, int* __restrict__ cnt, int* __restrict__ list)
{
    __shared__ int s_wsum[16];
    const int t    = threadIdx.x;
    const int lane = t & 63;
    const int wvv  = t >> 6;            // 0..15
    const int bkt  = blockIdx.x;        // 0..69
    const int b    = (bkt >= NC) ? 1 : 0;
    const int l    = bkt - b*NC;
    const int* lp  = lab + b*NPIX;

    // pass 1: count matches (coalesced interleaved)
    int m = 0;
    #pragma unroll
    for (int j = 0; j < 16; ++j) m += (lp[j*1024 + t] == l) ? 1 : 0;

    // inclusive wave scan -> exclusive block prefix
    int v = m;
    #pragma unroll
    for (int d = 1; d < 64; d <<= 1) {
        int o = __shfl_up(v, d);
        if (lane >= d) v += o;
    }
    if (lane == 63) s_wsum[wvv] = v;
    __syncthreads();
    int wbase = 0;
    #pragma unroll
    for (int k = 0; k < 16; ++k) wbase += (k < wvv) ? s_wsum[k] : 0;
    int base = wbase + v - m;           // exclusive prefix for this thread
    if (t == 0) {
        int s = 0;
        #pragma unroll
        for (int k = 0; k < 16; ++k) s += s_wsum[k];
        cnt[bkt] = s;
    }

    // pass 2: scatter pixel ids
    int* dst = list + bkt*LISTST;
    int o = base;
    #pragma unroll
    for (int j = 0; j < 16; ++j) {
        int p = j*1024 + t;
        if (lp[p] == l) dst[o++] = p;
    }
}

#define FMA_PX(A, XV) \
    A.x = fmaf((XV), qv.x, A.x); \
    A.y = fmaf((XV), qv.y, A.y); \
    A.z = fmaf((XV), qv.z, A.z); \
    A.w = fmaf((XV), qv.w, A.w);

// Kernel 2: label-grouped matvec, 32-pixel chunks (2x tasks of round 5 -> better load
// balance + shorter per-task critical path; one W sweep per wave instead of two).
// Stage 32 pixels transposed into LDS [c][p] stride 36; wave wv owns pixels wv*8..wv*8+7.
// Lane (i15,ihi): o-quad 4*i15, c = 4*tt+ihi; float4 LDS reads hit disjoint bank quads.
// Stats -> gpad (one 64B line per (b,o)) via fire-and-forget atomics.
__global__ __launch_bounds__(256) void mv_kernel(
    const float* __restrict__ Wt, const float* __restrict__ bt,
    const float* __restrict__ xT, const int* __restrict__ cnt,
    const int* __restrict__ list, float* __restrict__ yT,
    float* __restrict__ gpad)
{
    __shared__ __align__(16) float s_xh[64*MSTR];   // [c][p]
    __shared__ int   s_pib[32];
    __shared__ float s_red[4][64][2];
    __shared__ int   s_ntask;

    const int t    = threadIdx.x;
    const int wv   = t >> 6;
    const int lane = t & 63;
    const int i15  = lane & 15;
    const int ihi  = lane >> 4;

    // tight task bound from max bucket count (wave 0)
    if (t < 64) {
        int c1 = cnt[(lane < NBKT) ? lane : (NBKT-1)];
        int c2 = cnt[(lane < (NBKT-64)) ? 64 + lane : (NBKT-1)];
        int m  = c1 > c2 ? c1 : c2;
        #pragma unroll
        for (int d = 32; d >= 1; d >>= 1) {
            int o = __shfl_xor(m, d);
            m = m > o ? m : o;
        }
        if (lane == 0) s_ntask = NBKT * ((m + 31) >> 5);
    }
    __syncthreads();
    const int ntask = s_ntask;

    for (int task = blockIdx.x; task < ntask; task += gridDim.x) {
        const int bkt   = task % NBKT;       // bucket-fastest: chunk 0 of all buckets first
        const int chunk = task / NBKT;
        const int n     = cnt[bkt];
        const int base  = chunk << 5;
        if (base >= n) continue;             // block-uniform
        const int b = (bkt >= NC) ? 1 : 0;
        const int l = bkt - b*NC;

        __syncthreads();   // protect s_xh/s_red from previous task's readers

        // ---- stage 32 pixels transposed into s_xh[c][p] + pixel ids ----
        {
            const int p   = t & 31;          // pixel in chunk
            const int e   = t >> 5;          // channel-eighth 0..7
            const int pi  = base + p;
            const int pib = list[bkt*LISTST + ((pi < n) ? pi : (n-1))];
            if (e == 0) s_pib[p] = pib;
            const float* xp = xT + (((size_t)b*NPIX + pib) << 6) + (e << 3);
            float4 v0 = ((const float4*)xp)[0];
            float4 v1 = ((const float4*)xp)[1];
            const int c = e << 3;
            s_xh[(c+0)*MSTR + p] = v0.x;
            s_xh[(c+1)*MSTR + p] = v0.y;
            s_xh[(c+2)*MSTR + p] = v0.z;
            s_xh[(c+3)*MSTR + p] = v0.w;
            s_xh[(c+4)*MSTR + p] = v1.x;
            s_xh[(c+5)*MSTR + p] = v1.y;
            s_xh[(c+6)*MSTR + p] = v1.z;
            s_xh[(c+7)*MSTR + p] = v1.w;
        }
        __syncthreads();

        // ---- compute: wave wv owns pixels wv*8..wv*8+7 ----
        const float4* __restrict__ W4 = ((const float4*)(Wt + (size_t)l*4096)) + lane;
        const float4 bb = *((const float4*)(bt + (size_t)l*64) + i15);
        const int p0 = wv << 3;

        float4 a[8];
        #pragma unroll
        for (int pj = 0; pj < 8; ++pj) a[pj] = make_float4(0,0,0,0);

        #pragma unroll
        for (int tt = 0; tt < 16; ++tt) {
            const float4 qv = W4[tt << 6];                 // c = 4tt+ihi, o-quad 4*i15
            const int    c  = (tt << 2) + ihi;
            const float4 xa = *(const float4*)&s_xh[c*MSTR + p0];      // pixels p0..p0+3
            const float4 xb = *(const float4*)&s_xh[c*MSTR + p0 + 4];  // pixels p0+4..p0+7
            FMA_PX(a[0], xa.x) FMA_PX(a[1], xa.y) FMA_PX(a[2], xa.z) FMA_PX(a[3], xa.w)
            FMA_PX(a[4], xb.x) FMA_PX(a[5], xb.y) FMA_PX(a[6], xb.z) FMA_PX(a[7], xb.w)
        }

        // reduce partial c-subsets across the 4 ihi row-groups
        #pragma unroll
        for (int pj = 0; pj < 8; ++pj) {
            a[pj].x += __shfl_xor(a[pj].x, 16); a[pj].y += __shfl_xor(a[pj].y, 16);
            a[pj].z += __shfl_xor(a[pj].z, 16); a[pj].w += __shfl_xor(a[pj].w, 16);
            a[pj].x += __shfl_xor(a[pj].x, 32); a[pj].y += __shfl_xor(a[pj].y, 32);
            a[pj].z += __shfl_xor(a[pj].z, 32); a[pj].w += __shfl_xor(a[pj].w, 32);
        }

        float4 sumv = make_float4(0,0,0,0), ssv = make_float4(0,0,0,0);
        if (ihi == 0) {
            #pragma unroll
            for (int pj = 0; pj < 8; ++pj) {
                const bool  vld = (base + p0 + pj) < n;      // uniform over active lanes
                const float msk = vld ? 1.0f : 0.0f;
                float y0 = (a[pj].x + bb.x) * msk;
                float y1 = (a[pj].y + bb.y) * msk;
                float y2 = (a[pj].z + bb.z) * msk;
                float y3 = (a[pj].w + bb.w) * msk;
                if (vld) {
                    float* yp = yT + (((size_t)b*NPIX + s_pib[p0+pj]) << 6) + (i15 << 2);
                    *(float4*)yp = make_float4(y0, y1, y2, y3);
                }
                sumv.x += y0; ssv.x += y0*y0;
                sumv.y += y1; ssv.y += y1*y1;
                sumv.z += y2; ssv.z += y2*y2;
                sumv.w += y3; ssv.w += y3*y3;
            }
            const int o = i15 << 2;
            s_red[wv][o+0][0] = sumv.x; s_red[wv][o+0][1] = ssv.x;
            s_red[wv][o+1][0] = sumv.y; s_red[wv][o+1][1] = ssv.y;
            s_red[wv][o+2][0] = sumv.z; s_red[wv][o+2][1] = ssv.z;
            s_red[wv][o+3][0] = sumv.w; s_red[wv][o+3][1] = ssv.w;
        }
        __syncthreads();
        if (t < 64) {
            float S  = s_red[0][t][0] + s_red[1][t][0] + s_red[2][t][0] + s_red[3][t][0];
            float SS = s_red[0][t][1] + s_red[1][t][1] + s_red[2][t][1] + s_red[3][t][1];
            float* gp = gpad + (((b << 6) + t) << 4);   // private 64B line per (b,o)
            atomicAdd(gp + 0, S);                        // fire-and-forget (no return use)
            atomicAdd(gp + 1, SS);
        }
    }
}

// Kernel 3: finalize stats per block + transpose yT -> out with instance-norm + leaky relu.
__global__ __launch_bounds__(256) void norm_kernel(
    const float* __restrict__ yT, const float* __restrict__ gpad,
    float* __restrict__ out)
{
    __shared__ float s_t[64*65];   // [o][w] pad 65
    __shared__ float s_mean[64];
    __shared__ float s_rstd[64];

    const int t    = threadIdx.x;
    const int tile = blockIdx.x;   // 512: b(2) x h(128) x wt(2)
    const int b    = tile >> 8;
    const int rem  = tile & 255;
    const int h    = rem >> 1;
    const int w0   = (rem & 1) << 6;

    if (t < 64) {
        const float invN = 1.0f/16384.0f;
        const float* gp = gpad + (((b << 6) + t) << 4);
        float mean = gp[0] * invN;
        float var  = gp[1] * invN - mean*mean;
        s_mean[t] = mean;
        s_rstd[t] = rsqrtf(var + 1e-5f);
    }
    {
        const int p = t >> 2, q = t & 3;   // pixel in tile, o-quarter
        const float4* yp = (const float4*)(yT + (((size_t)b*NPIX + h*WW + w0 + p) << 6) + (q << 4));
        #pragma unroll
        for (int j = 0; j < 4; ++j) {
            float4 v = yp[j];
            int o = (q << 4) + (j << 2);
            s_t[(o+0)*65 + p] = v.x;
            s_t[(o+1)*65 + p] = v.y;
            s_t[(o+2)*65 + p] = v.z;
            s_t[(o+3)*65 + p] = v.w;
        }
    }
    __syncthreads();
    {
        const int o = t >> 2, q = t & 3;
        const float mean = s_mean[o];
        const float r    = s_rstd[o];
        float* op = out + (((size_t)(b*OO + o)*HH + h)*WW) + w0 + (q << 4);
        #pragma unroll
        for (int j = 0; j < 4; ++j) {
            int wq = (q << 4) + (j << 2);
            float4 v;
            v.x = s_t[o*65 + wq + 0];
            v.y = s_t[o*65 + wq + 1];
            v.z = s_t[o*65 + wq + 2];
            v.w = s_t[o*65 + wq + 3];
            float a_;
            a_ = (v.x - mean) * r; v.x = (a_ >= 0.f) ? a_ : 0.01f*a_;
            a_ = (v.y - mean) * r; v.y = (a_ >= 0.f) ? a_ : 0.01f*a_;
            a_ = (v.z - mean) * r; v.z = (a_ >= 0.f) ? a_ : 0.01f*a_;
            a_ = (v.w - mean) * r; v.w = (a_ >= 0.f) ? a_ : 0.01f*a_;
            ((float4*)op)[j] = v;
        }
    }
}

extern "C" void kernel_launch(void* const* d_in, const int* in_sizes, int n_in,
                              void* d_out, int out_size, void* d_ws, size_t ws_size,
                              hipStream_t stream) {
    const float* x      = (const float*)d_in[0];
    const float* layout = (const float*)d_in[1];
    const float* pr     = (const float*)d_in[2];
    const float* cw     = (const float*)d_in[3];
    const float* cb     = (const float*)d_in[4];
    const float* Wt     = (const float*)d_in[5];
    const float* bt     = (const float*)d_in[6];
    const float* pl     = (const float*)d_in[7];
    float* out = (float*)d_out;

    char*  ws   = (char*)d_ws;
    float* gpad = (float*)ws;                       // [128][16] f32, 8 KB (zeroed by prep)
    int*   cnt  = (int*)(ws + 8192);                // [70]
    int*   lab  = (int*)(ws + 16384);               // [2][16384]
    int*   list = (int*)(ws + (256u << 10));        // [70][16384]
    float* xT   = (float*)(ws + (8u  << 20));
    float* yT   = (float*)(ws + (16u << 20));

    prep_kernel<<<1024,  256, 0, stream>>>(x, layout, pr, cw, cb, pl, xT, lab, gpad);
    bin_kernel <<<  70, 1024, 0, stream>>>(lab, cnt, list);
    mv_kernel  <<<1536,  256, 0, stream>>>(Wt, bt, xT, cnt, list, yT, gpad);
    norm_kernel<<< 512,  256, 0, stream>>>(yT, gpad, out);
}

// Round 8
// 109.253 us; speedup vs baseline: 2.6855x; 1.1737x over previous
//
#include <hip/hip_runtime.h>

#define HH 128
#define WW 128
#define CC 64
#define OO 64
#define NC 35
#define NPIX (HH*WW)        // per-batch pixels = 16384
#define LISTST NPIX
#define NBKT (2*NC)         // 70 buckets (b,label)
#define XSTR 68             // mv LDS row stride: 64 pixels + 4 pad (conflict-free, r3/r5-proven)
#define TST  17920          // partial-slot row stride = NBKT * ceil(NPIX/64) = 70*256

// Workspace layout (no memset needed; every cell written before read each iteration):
//   [0,     280)    cnt[70]            (bin, plain store)
//   [1024,  2048)   stats[128][2]      (stats_kernel)
//   [16384, 147456) lab[2*16384] int   (prep)
//   [256 KiB, +4.6 MiB) list[70*16384] int (bin)
//   [ 8 MiB)        xT : (b,pix,c) = x + conv-scalar, pixel-major (prep)
//   [16 MiB)        yT : (b,pix,o) pre-norm output, pixel-major (mv)
//   [32 MiB)        psum[64][TST]      (mv: per-task partial sums; zeros for skipped)
//   [48 MiB)        pss [64][TST]      (mv: per-task partial sumsq)

// Kernel 1: conv scalar + argmax -> lab + transpose x(+s) -> xT. NO atomics.
__global__ __launch_bounds__(256) void prep_kernel(
    const float* __restrict__ x, const float* __restrict__ layout,
    const float* __restrict__ pr, const float* __restrict__ cw,
    const float* __restrict__ cb, const float* __restrict__ pl,
    float* __restrict__ xT, int* __restrict__ lab)
{
    __shared__ float s_xh[64*33];   // [c][p] stride 33, 32 pixels -> conflict-free
    __shared__ float s_s[32];

    const int t    = threadIdx.x;
    const int wv   = t >> 6;
    const int lane = t & 63;
    const int tile = blockIdx.x;     // 1024: b(2) x h(128) x wq(4)
    const int b    = tile >> 9;
    const int rem  = tile & 511;
    const int h    = rem >> 2;
    const int w0   = (rem & 3) << 5;

    // conv scalar s for 32 pixels (wave 0, lanes 0..31)
    if (wv == 0 && lane < 32) {
        int w = w0 + lane;
        float pxv = (float)h * (2.0f/128.0f) - 1.0f;
        float pyv = (float)w * (2.0f/128.0f) - 1.0f;
        float pl0 = pl[h*WW + w];
        float pl1 = pl[NPIX + h*WW + w];
        float pr0 = pr[((b*2+0)*HH + h)*WW + w];
        float pr1 = pr[((b*2+1)*HH + h)*WW + w];
        int kx = w % 3, kyy = h % 3;
        const float C1 = -0.5f, S1 = 0.86602540378443864676f;
        float xcv = (kx==0)  ? 1.0f : C1;
        float xsv = (kx==0)  ? 0.0f : ((kx==1)  ? S1 : -S1);
        float ycv = (kyy==0) ? 1.0f : C1;
        float ysv = (kyy==0) ? 0.0f : ((kyy==1) ? S1 : -S1);
        s_s[lane] = cb[0] + pxv*cw[0] + pyv*cw[1] + pl0*cw[2] + pl1*cw[3]
                  + pr0*cw[4] + pr1*cw[5] + xcv*cw[6] + xsv*cw[7]
                  + ycv*cw[8] + ysv*cw[9];
    }

    // argmax over layout channels (wave 1, lanes 0..31); first-max wins like jnp.argmax
    if (wv == 1 && lane < 32) {
        int w = w0 + lane;
        const float* lp = layout + ((size_t)(b*NC)*HH + h)*WW + w;
        float best = lp[0]; int bi = 0;
        #pragma unroll
        for (int c = 1; c < NC; ++c) {
            float v = lp[(size_t)c*NPIX];
            if (v > best) { best = v; bi = c; }
        }
        lab[b*NPIX + h*WW + w] = bi;      // plain coalesced store
    }

    // stage raw x into LDS (coalesced)
    {
        int p = t & 31, c0 = t >> 5;
        const float* xp = x + ((size_t)(b*CC)*HH + h)*WW + w0 + p;
        #pragma unroll
        for (int k = 0; k < 8; ++k) {
            int c = c0 + 8*k;
            s_xh[c*33 + p] = xp[(size_t)c*NPIX];
        }
    }
    __syncthreads();

    // transpose-write xT[pix][c] = x + s  (coalesced 8 KB/block contiguous)
    {
        int p = t >> 3, c0 = (t & 7) << 3;
        float sp = s_s[p];
        float4 a, d;
        a.x = s_xh[(c0+0)*33+p] + sp;
        a.y = s_xh[(c0+1)*33+p] + sp;
        a.z = s_xh[(c0+2)*33+p] + sp;
        a.w = s_xh[(c0+3)*33+p] + sp;
        d.x = s_xh[(c0+4)*33+p] + sp;
        d.y = s_xh[(c0+5)*33+p] + sp;
        d.z = s_xh[(c0+6)*33+p] + sp;
        d.w = s_xh[(c0+7)*33+p] + sp;
        float* dst = xT + (((size_t)b*NPIX + h*WW + w0 + p) << 6) + c0;
        *(float4*)dst       = a;
        *(float4*)(dst + 4) = d;
    }
}

// Kernel 1b: bucket the pixels. One 1024-thread block per (b,label) bucket; shfl
// prefix-scan; plain stores only (zero atomics).
__global__ __launch_bounds__(1024) void bin_kernel(
    const int* __restrict__ lab, int* __restrict__ cnt, int* __restrict__ list)
{
    __shared__ int s_wsum[16];
    const int t    = threadIdx.x;
    const int lane = t & 63;
    const int wvv  = t >> 6;            // 0..15
    const int bkt  = blockIdx.x;        // 0..69
    const int b    = (bkt >= NC) ? 1 : 0;
    const int l    = bkt - b*NC;
    const int* lp  = lab + b*NPIX;

    int m = 0;
    #pragma unroll
    for (int j = 0; j < 16; ++j) m += (lp[j*1024 + t] == l) ? 1 : 0;

    int v = m;
    #pragma unroll
    for (int d = 1; d < 64; d <<= 1) {
        int o = __shfl_up(v, d);
        if (lane >= d) v += o;
    }
    if (lane == 63) s_wsum[wvv] = v;
    __syncthreads();
    int wbase = 0;
    #pragma unroll
    for (int k = 0; k < 16; ++k) wbase += (k < wvv) ? s_wsum[k] : 0;
    int base = wbase + v - m;           // exclusive prefix for this thread
    if (t == 0) {
        int s = 0;
        #pragma unroll
        for (int k = 0; k < 16; ++k) s += s_wsum[k];
        cnt[bkt] = s;
    }

    int* dst = list + bkt*LISTST;
    int o = base;
    #pragma unroll
    for (int j = 0; j < 16; ++j) {
        int p = j*1024 + t;
        if (lp[p] == l) dst[o++] = p;
    }
}

#define FMA_PX(A, XV) \
    A.x = fmaf((XV), qv.x, A.x); \
    A.y = fmaf((XV), qv.y, A.y); \
    A.z = fmaf((XV), qv.z, A.z); \
    A.w = fmaf((XV), qv.w, A.w);

// Kernel 2: label-grouped matvec, 64-pixel block tasks (r3/r5-proven geometry).
// Stats: per-task partials to psum/pss[o][task] -- PLAIN STORES, zero atomics.
// Skipped tasks (base >= n) write zero partials so slots are dense.
__global__ __launch_bounds__(256) void mv_kernel(
    const float* __restrict__ Wt, const float* __restrict__ bt,
    const float* __restrict__ xT, const int* __restrict__ cnt,
    const int* __restrict__ list, float* __restrict__ yT,
    float* __restrict__ psum, float* __restrict__ pss)
{
    __shared__ __align__(16) float s_xh[64*XSTR];   // [c][p]
    __shared__ int   s_pib[64];
    __shared__ float s_red[4][64][2];
    __shared__ int   s_ntask;

    const int t    = threadIdx.x;
    const int wv   = t >> 6;
    const int lane = t & 63;
    const int i15  = lane & 15;
    const int ihi  = lane >> 4;

    if (t < 64) {   // tight task bound from max bucket count
        int c1 = cnt[(lane < NBKT) ? lane : (NBKT-1)];
        int c2 = cnt[(lane < (NBKT-64)) ? 64 + lane : (NBKT-1)];
        int m  = c1 > c2 ? c1 : c2;
        #pragma unroll
        for (int d = 32; d >= 1; d >>= 1) {
            int o = __shfl_xor(m, d);
            m = m > o ? m : o;
        }
        if (lane == 0) s_ntask = NBKT * ((m + 63) >> 6);
    }
    __syncthreads();
    const int ntask = s_ntask;

    for (int task = blockIdx.x; task < ntask; task += gridDim.x) {
        const int bkt   = task % NBKT;       // bucket-fastest
        const int chunk = task / NBKT;
        const int n     = cnt[bkt];
        const int base  = chunk << 6;
        if (base >= n) {                     // dead slot: zero partials, move on
            if (t < 64) {
                psum[(size_t)t*TST + task] = 0.0f;
                pss [(size_t)t*TST + task] = 0.0f;
            }
            continue;
        }
        const int b = (bkt >= NC) ? 1 : 0;
        const int l = bkt - b*NC;

        __syncthreads();   // protect s_xh/s_red from previous task's readers

        // ---- stage 64 pixels transposed into s_xh[c][p] + pixel ids ----
        {
            const int p   = t & 63;
            const int q   = t >> 6;
            const int pi  = base + p;
            const int pib = list[bkt*LISTST + ((pi < n) ? pi : (n-1))];
            if (q == 0) s_pib[p] = pib;
            const float* xp = xT + (((size_t)b*NPIX + pib) << 6) + (q << 4);
            #pragma unroll
            for (int j = 0; j < 4; ++j) {
                float4 v = ((const float4*)xp)[j];
                const int c = (q << 4) + (j << 2);
                s_xh[(c+0)*XSTR + p] = v.x;
                s_xh[(c+1)*XSTR + p] = v.y;
                s_xh[(c+2)*XSTR + p] = v.z;
                s_xh[(c+3)*XSTR + p] = v.w;
            }
        }
        __syncthreads();

        // ---- compute: wave wv owns pixels wv*16..wv*16+15, two groups of 8 ----
        const float4* __restrict__ W4 = ((const float4*)(Wt + (size_t)l*4096)) + lane;
        const float4 bb = *((const float4*)(bt + (size_t)l*64) + i15);
        float4 sumv = make_float4(0,0,0,0), ssv = make_float4(0,0,0,0);

        #pragma unroll
        for (int g = 0; g < 2; ++g) {
            const int p0 = (wv << 4) + (g << 3);
            float4 a[8];
            #pragma unroll
            for (int pj = 0; pj < 8; ++pj) a[pj] = make_float4(0,0,0,0);

            #pragma unroll
            for (int tt = 0; tt < 16; ++tt) {
                const float4 qv = W4[tt << 6];                 // c = 4tt+ihi, o-quad 4*i15
                const int    c  = (tt << 2) + ihi;
                const float4 xa = *(const float4*)&s_xh[c*XSTR + p0];
                const float4 xb = *(const float4*)&s_xh[c*XSTR + p0 + 4];
                FMA_PX(a[0], xa.x) FMA_PX(a[1], xa.y) FMA_PX(a[2], xa.z) FMA_PX(a[3], xa.w)
                FMA_PX(a[4], xb.x) FMA_PX(a[5], xb.y) FMA_PX(a[6], xb.z) FMA_PX(a[7], xb.w)
            }

            #pragma unroll
            for (int pj = 0; pj < 8; ++pj) {
                a[pj].x += __shfl_xor(a[pj].x, 16); a[pj].y += __shfl_xor(a[pj].y, 16);
                a[pj].z += __shfl_xor(a[pj].z, 16); a[pj].w += __shfl_xor(a[pj].w, 16);
                a[pj].x += __shfl_xor(a[pj].x, 32); a[pj].y += __shfl_xor(a[pj].y, 32);
                a[pj].z += __shfl_xor(a[pj].z, 32); a[pj].w += __shfl_xor(a[pj].w, 32);
            }

            if (ihi == 0) {
                #pragma unroll
                for (int pj = 0; pj < 8; ++pj) {
                    const bool  vld = (base + p0 + pj) < n;
                    const float msk = vld ? 1.0f : 0.0f;
                    float y0 = (a[pj].x + bb.x) * msk;
                    float y1 = (a[pj].y + bb.y) * msk;
                    float y2 = (a[pj].z + bb.z) * msk;
                    float y3 = (a[pj].w + bb.w) * msk;
                    if (vld) {
                        float* yp = yT + (((size_t)b*NPIX + s_pib[p0+pj]) << 6) + (i15 << 2);
                        *(float4*)yp = make_float4(y0, y1, y2, y3);
                    }
                    sumv.x += y0; ssv.x += y0*y0;
                    sumv.y += y1; ssv.y += y1*y1;
                    sumv.z += y2; ssv.z += y2*y2;
                    sumv.w += y3; ssv.w += y3*y3;
                }
            }
        }

        if (ihi == 0) {
            const int o = i15 << 2;
            s_red[wv][o+0][0] = sumv.x; s_red[wv][o+0][1] = ssv.x;
            s_red[wv][o+1][0] = sumv.y; s_red[wv][o+1][1] = ssv.y;
            s_red[wv][o+2][0] = sumv.z; s_red[wv][o+2][1] = ssv.z;
            s_red[wv][o+3][0] = sumv.w; s_red[wv][o+3][1] = ssv.w;
        }
        __syncthreads();
        if (t < 64) {
            float S  = s_red[0][t][0] + s_red[1][t][0] + s_red[2][t][0] + s_red[3][t][0];
            float SS = s_red[0][t][1] + s_red[1][t][1] + s_red[2][t][1] + s_red[3][t][1];
            psum[(size_t)t*TST + task] = S;     // plain store, unique slot
            pss [(size_t)t*TST + task] = SS;
        }
    }
}

// Kernel 2b: reduce per-task partials -> mean & rsqrt(var+eps). 128 blocks, no atomics.
__global__ __launch_bounds__(256) void stats_kernel(
    const float* __restrict__ psum, const float* __restrict__ pss,
    const int* __restrict__ cnt, float* __restrict__ stats)
{
    __shared__ float s_red[4][2];
    __shared__ int   s_nt;
    const int e    = blockIdx.x;       // 0..127: b = e>>6, o = e&63
    const int b    = e >> 6;
    const int o    = e & 63;
    const int t    = threadIdx.x;
    const int lane = t & 63;
    const int wv   = t >> 6;

    if (t < 64) {
        int c1 = cnt[(lane < NBKT) ? lane : (NBKT-1)];
        int c2 = cnt[(lane < (NBKT-64)) ? 64 + lane : (NBKT-1)];
        int m  = c1 > c2 ? c1 : c2;
        #pragma unroll
        for (int d = 32; d >= 1; d >>= 1) {
            int x = __shfl_xor(m, d);
            m = m > x ? m : x;
        }
        if (lane == 0) s_nt = NBKT * ((m + 63) >> 6);
    }
    __syncthreads();
    const int ntask = s_nt;

    float S = 0.0f, SS = 0.0f;
    const float* pr_ = psum + (size_t)o*TST;
    const float* pq_ = pss  + (size_t)o*TST;
    for (int i = t; i < ntask; i += 256) {
        int bkt = i % NBKT;
        int bi  = (bkt >= NC) ? 1 : 0;
        if (bi == b) { S += pr_[i]; SS += pq_[i]; }
    }
    #pragma unroll
    for (int d = 32; d >= 1; d >>= 1) {
        S += __shfl_xor(S, d);
        SS += __shfl_xor(SS, d);
    }
    if (lane == 0) { s_red[wv][0] = S; s_red[wv][1] = SS; }
    __syncthreads();
    if (t == 0) {
        float s  = s_red[0][0] + s_red[1][0] + s_red[2][0] + s_red[3][0];
        float ss = s_red[0][1] + s_red[1][1] + s_red[2][1] + s_red[3][1];
        const float invN = 1.0f/16384.0f;
        float mean = s * invN;
        float var  = ss * invN - mean*mean;
        stats[e*2+0] = mean;
        stats[e*2+1] = rsqrtf(var + 1e-5f);
    }
}

// Kernel 3: transpose yT -> out with instance-norm + leaky relu.
__global__ __launch_bounds__(256) void norm_kernel(
    const float* __restrict__ yT, const float* __restrict__ stats,
    float* __restrict__ out)
{
    __shared__ float s_t[64*65];   // [o][w] pad 65
    __shared__ float s_mean[64];
    __shared__ float s_rstd[64];

    const int t    = threadIdx.x;
    const int tile = blockIdx.x;   // 512: b(2) x h(128) x wt(2)
    const int b    = tile >> 8;
    const int rem  = tile & 255;
    const int h    = rem >> 1;
    const int w0   = (rem & 1) << 6;

    if (t < 64) {
        const int e = (b << 6) + t;
        s_mean[t] = stats[e*2+0];
        s_rstd[t] = stats[e*2+1];
    }
    {
        const int p = t >> 2, q = t & 3;   // pixel in tile, o-quarter
        const float4* yp = (const float4*)(yT + (((size_t)b*NPIX + h*WW + w0 + p) << 6) + (q << 4));
        #pragma unroll
        for (int j = 0; j < 4; ++j) {
            float4 v = yp[j];
            int o = (q << 4) + (j << 2);
            s_t[(o+0)*65 + p] = v.x;
            s_t[(o+1)*65 + p] = v.y;
            s_t[(o+2)*65 + p] = v.z;
            s_t[(o+3)*65 + p] = v.w;
        }
    }
    __syncthreads();
    {
        const int o = t >> 2, q = t & 3;
        const float mean = s_mean[o];
        const float r    = s_rstd[o];
        float* op = out + (((size_t)(b*OO + o)*HH + h)*WW) + w0 + (q << 4);
        #pragma unroll
        for (int j = 0; j < 4; ++j) {
            int wq = (q << 4) + (j << 2);
            float4 v;
            v.x = s_t[o*65 + wq + 0];
            v.y = s_t[o*65 + wq + 1];
            v.z = s_t[o*65 + wq + 2];
            v.w = s_t[o*65 + wq + 3];
            float a_;
            a_ = (v.x - mean) * r; v.x = (a_ >= 0.f) ? a_ : 0.01f*a_;
            a_ = (v.y - mean) * r; v.y = (a_ >= 0.f) ? a_ : 0.01f*a_;
            a_ = (v.z - mean) * r; v.z = (a_ >= 0.f) ? a_ : 0.01f*a_;
            a_ = (v.w - mean) * r; v.w = (a_ >= 0.f) ? a_ : 0.01f*a_;
            ((float4*)op)[j] = v;
        }
    }
}

extern "C" void kernel_launch(void* const* d_in, const int* in_sizes, int n_in,
                              void* d_out, int out_size, void* d_ws, size_t ws_size,
                              hipStream_t stream) {
    const float* x      = (const float*)d_in[0];
    const float* layout = (const float*)d_in[1];
    const float* pr     = (const float*)d_in[2];
    const float* cw     = (const float*)d_in[3];
    const float* cb     = (const float*)d_in[4];
    const float* Wt     = (const float*)d_in[5];
    const float* bt     = (const float*)d_in[6];
    const float* pl     = (const float*)d_in[7];
    float* out = (float*)d_out;

    char*  ws    = (char*)d_ws;
    int*   cnt   = (int*)ws;                        // [70]
    float* stats = (float*)(ws + 1024);             // [128][2]
    int*   lab   = (int*)(ws + 16384);              // [2][16384]
    int*   list  = (int*)(ws + (256u << 10));       // [70][16384]
    float* xT    = (float*)(ws + (8u  << 20));
    float* yT    = (float*)(ws + (16u << 20));
    float* psum  = (float*)(ws + (32u << 20));      // [64][TST]
    float* pss   = (float*)(ws + (48u << 20));      // [64][TST]

    prep_kernel <<<1024,  256, 0, stream>>>(x, layout, pr, cw, cb, pl, xT, lab);
    bin_kernel  <<<  70, 1024, 0, stream>>>(lab, cnt, list);
    mv_kernel   <<<1024,  256, 0, stream>>>(Wt, bt, xT, cnt, list, yT, psum, pss);
    stats_kernel<<< 128,  256, 0, stream>>>(psum, pss, cnt, stats);
    norm_kernel <<< 512,  256, 0, stream>>>(yT, stats, out);
}